// Round 7
// baseline (298.710 us; speedup 1.0000x reference)
//
#include <hip/hip_runtime.h>

#define NNODES 50000
#define DIN 128
#define DHID 128
#define DOUT 128
#define NEG_SLOPE 0.01f
#define NT 12500   // 1,600,000 rows / 128
#define GG 256     // persistent grid: 1 block per CU

typedef _Float16 f16x8 __attribute__((ext_vector_type(8)));
typedef _Float16 f16x4 __attribute__((ext_vector_type(4)));
typedef float f32x4 __attribute__((ext_vector_type(4)));

// d_ws layout (halves):
//  WqB hi: [ct(8)][g(4)][l(64)][8]   = 16384 halves
//  WqB lo: 16384
//  WwB hi: [ct(8)][g(8)][l(64)][8]   = 32768 halves
//  WwB lo: 32768
#define WS_WQ_HI 0
#define WS_WQ_LO 16384
#define WS_WW_HI 32768
#define WS_WW_LO 65536

__device__ __forceinline__ void gload_lds16(const float* g, float* lds) {
    __builtin_amdgcn_global_load_lds(
        (const __attribute__((address_space(1))) void*)g,
        (__attribute__((address_space(3))) void*)lds, 16, 0, 0);
}

// ---------------------------------------------------------------- kernel 0
// Convert weights to fp16 hi/lo fragment slabs.
// Fragment convention (mfma_f32_16x16x32_f16):
//   A: row = l&15, k = (l>>4)*8 + j
//   B: col = l&15, k = (l>>4)*8 + j
//   D: col = l&15, row = (l>>4)*4 + r
__global__ void convert_weights(const float* __restrict__ Wq,
                                const float* __restrict__ Ww,
                                _Float16* __restrict__ ws) {
    int id = blockIdx.x * 256 + threadIdx.x;
    if (id < 2048) {  // Wq slots: B[k][col] = Wq[col][k]
        int s  = id;
        int l  = s & 63;
        int g  = (s >> 6) & 3;
        int ct = s >> 8;
        int col = ct * 16 + (l & 15);
        int k0  = g * 32 + (l >> 4) * 8;
        const float* src = Wq + col * DIN + k0;
        f16x8 vh, vl;
#pragma unroll
        for (int j = 0; j < 8; ++j) {
            float v = src[j];
            _Float16 h = (_Float16)v;
            vh[j] = h;
            vl[j] = (_Float16)(v - (float)h);
        }
        *(f16x8*)(ws + WS_WQ_HI + s * 8) = vh;
        *(f16x8*)(ws + WS_WQ_LO + s * 8) = vl;
    } else if (id < 2048 + 4096) {  // Ww slots: B2[k][o] = Ww[o][k]
        int s  = id - 2048;
        int l  = s & 63;
        int g  = (s >> 6) & 7;
        int ct = s >> 9;
        int col = ct * 16 + (l & 15);
        int k0  = g * 32 + (l >> 4) * 8;
        const float* src = Ww + col * (DIN + DHID) + k0;
        f16x8 vh, vl;
#pragma unroll
        for (int j = 0; j < 8; ++j) {
            float v = src[j];
            _Float16 h = (_Float16)v;
            vh[j] = h;
            vl[j] = (_Float16)(v - (float)h);
        }
        *(f16x8*)(ws + WS_WW_HI + s * 8) = vh;
        *(f16x8*)(ws + WS_WW_LO + s * 8) = vl;
    }
}

// ---------------------------------------------------------------- kernel 1
// GEMM1 + leaky + alpha-weighted mean -> hagg (= d_out).
// Persistent ring pipeline, 8 waves (2 row-groups x 4 col-groups), wave
// tile 64x32, ~150 VGPR. Ring: 4 x 16KB LDS slabs; at chunk c stage chunk
// c+3 (wrapping into the next tile). Prologue ends with a full vmcnt(0)
// drain + barrier (iter-0 order-robust). Steady-state queue per tile
// (sched_barrier(0)-pinned): [S(2)]x4, W(2), A(4) -> waits
// vmcnt(10,10,10,4).
// R4/R5/R6 BUG (fixed here): the STAGE refactor dropped the global column
// offset c*32 — every slab was staged from k-chunk 0. Deterministic,
// schedule-independent, hence the bit-identical absmax across 3 rounds.
__global__ __launch_bounds__(512, 2) void gemm1_agg(
    const float* __restrict__ hng,    // [NNODES*32][128]
    const float* __restrict__ alpha,  // [NNODES*32]
    const float* __restrict__ bq,     // [128]
    const _Float16* __restrict__ ws,
    float* __restrict__ hagg)         // [NNODES][128]
{
    __shared__ float As[4][4096];  // 4-slab ring, 64KB

    const int tid = threadIdx.x;
    const int l   = tid & 63;
    const int wid = tid >> 6;          // 0..7
    const int wr  = wid >> 2;          // 0..1  (row group: 64 rows)
    const int wc  = wid & 3;           // 0..3  (col group: 32 cols)
    const int r16 = l & 15;
    const int kg  = l >> 4;
    const int srow = l >> 3;                 // 0..7 within stage instr
    const int scol = ((l & 7) ^ srow) * 4;   // pre-swizzled src float offset
                                             // (within-chunk, 0..28)

    const _Float16* wqh = ws + WS_WQ_HI;
    const _Float16* wql = ws + WS_WQ_LO;

    // ---- permanent B fragments: 4 chunks x 2 col-tiles, hi+lo (64 VGPR)
    f16x8 bh[4][2], bl[4][2];
#pragma unroll
    for (int c = 0; c < 4; ++c)
#pragma unroll
        for (int ct = 0; ct < 2; ++ct) {
            int off = (((wc * 2 + ct) * 4 + c) * 64 + l) * 8;
            bh[c][ct] = *(const f16x8*)(wqh + off);
            bl[c][ct] = *(const f16x8*)(wql + off);
        }

    // per-lane global base for staging; per use add (Rb + {0,64})*DIN and
    // the chunk column offset c*32
    const float* hb = hng + (wid * 8 + srow) * DIN + scol;

#define STAGE(Rb, c)                                                          \
    do {                                                                      \
        gload_lds16(hb + (Rb)*DIN + (c) * 32, &As[c][(wid * 8) * 32]);        \
        gload_lds16(hb + ((Rb) + 64) * DIN + (c) * 32,                        \
                    &As[c][(64 + wid * 8) * 32]);                             \
    } while (0)

#define COMPUTE(c)                                                            \
    do {                                                                      \
        _Pragma("unroll")                                                     \
        for (int rt_ = 0; rt_ < 4; ++rt_) {                                   \
            int row_ = wr * 64 + rt_ * 16 + r16;                              \
            int sw_  = (r16 & 7) << 4;                                        \
            const char* rb_ = (const char*)&As[c][row_ * 32];                 \
            f32x4 v0_ = *(const f32x4*)(rb_ + ((kg * 32 + 0) ^ sw_));         \
            f32x4 v1_ = *(const f32x4*)(rb_ + ((kg * 32 + 16) ^ sw_));        \
            f16x8 ah_, al_;                                                   \
            _Pragma("unroll")                                                 \
            for (int j_ = 0; j_ < 4; ++j_) {                                  \
                _Float16 h_ = (_Float16)v0_[j_];                              \
                ah_[j_] = h_;                                                 \
                al_[j_] = (_Float16)(v0_[j_] - (float)h_);                    \
            }                                                                 \
            _Pragma("unroll")                                                 \
            for (int j_ = 0; j_ < 4; ++j_) {                                  \
                _Float16 h_ = (_Float16)v1_[j_];                              \
                ah_[j_ + 4] = h_;                                             \
                al_[j_ + 4] = (_Float16)(v1_[j_] - (float)h_);                \
            }                                                                 \
            _Pragma("unroll")                                                 \
            for (int ct_ = 0; ct_ < 2; ++ct_) {                               \
                acc[rt_][ct_] = __builtin_amdgcn_mfma_f32_16x16x32_f16(       \
                    ah_, bh[c][ct_], acc[rt_][ct_], 0, 0, 0);                 \
                acc[rt_][ct_] = __builtin_amdgcn_mfma_f32_16x16x32_f16(       \
                    ah_, bl[c][ct_], acc[rt_][ct_], 0, 0, 0);                 \
                acc[rt_][ct_] = __builtin_amdgcn_mfma_f32_16x16x32_f16(       \
                    al_, bh[c][ct_], acc[rt_][ct_], 0, 0, 0);                 \
            }                                                                 \
        }                                                                     \
    } while (0)

    long t  = blockIdx.x;
    long R0 = t * 128;

    // ---- prologue (issue order irrelevant — fully drained below)
    STAGE(R0, 0);
    STAGE(R0, 1);
    STAGE(R0, 2);
    float bqv[2];
#pragma unroll
    for (int ct = 0; ct < 2; ++ct)
        bqv[ct] = bq[wc * 32 + ct * 16 + r16];
    f32x4 av4[4];
#pragma unroll
    for (int rt = 0; rt < 4; ++rt)
        av4[rt] = *(const f32x4*)(alpha + R0 + wr * 64 + rt * 16 + kg * 4);
    // full drain: iter-0 wait ladder is order-robust
    asm volatile("s_waitcnt vmcnt(0)" ::: "memory");
    __builtin_amdgcn_s_barrier();
    __builtin_amdgcn_sched_barrier(0);

    for (;;) {
        const bool last = (t + GG >= NT);
        const long tn   = last ? t : t + GG;   // clamped prefetch target
        const long Rn   = tn * 128;

        f32x4 acc[4][2];
#pragma unroll
        for (int i = 0; i < 4; ++i)
#pragma unroll
            for (int j = 0; j < 2; ++j) acc[i][j] = (f32x4){0.f, 0.f, 0.f, 0.f};

        // ---- c0: need S(t,0); steady outstanding = S0,S1,S2,W,A = 12
        asm volatile("s_waitcnt vmcnt(10)" ::: "memory");
        __builtin_amdgcn_s_barrier();
        __builtin_amdgcn_sched_barrier(0);
        STAGE(R0, 3);
        __builtin_amdgcn_sched_barrier(0);
        COMPUTE(0);
        // ---- c1: need S(t,1); outstanding = S1,S2,W,A,S3 = 12
        asm volatile("s_waitcnt vmcnt(10)" ::: "memory");
        __builtin_amdgcn_s_barrier();
        __builtin_amdgcn_sched_barrier(0);
        STAGE(Rn, 0);
        __builtin_amdgcn_sched_barrier(0);
        COMPUTE(1);
        // ---- c2: need S(t,2); outstanding = S2,W,A,S3,Sn0 = 12
        asm volatile("s_waitcnt vmcnt(10)" ::: "memory");
        __builtin_amdgcn_s_barrier();
        __builtin_amdgcn_sched_barrier(0);
        STAGE(Rn, 1);
        __builtin_amdgcn_sched_barrier(0);
        COMPUTE(2);
        // ---- c3: need S(t,3) (also retires W,A); leaves Sn0,Sn1 = 4
        asm volatile("s_waitcnt vmcnt(4)" ::: "memory");
        __builtin_amdgcn_s_barrier();
        __builtin_amdgcn_sched_barrier(0);
        STAGE(Rn, 2);
        __builtin_amdgcn_sched_barrier(0);
        COMPUTE(3);
        __builtin_amdgcn_sched_barrier(0);

        // ---- epilogue tile t: +bq, leaky, *alpha, reduce 32 rows/node
        {
            float part[2][2] = {{0.f, 0.f}, {0.f, 0.f}};
            float apart[2] = {0.f, 0.f};
#pragma unroll
            for (int rt = 0; rt < 4; ++rt) {
                const int nl = rt >> 1;
#pragma unroll
                for (int r = 0; r < 4; ++r) {
                    float aw = av4[rt][r];
                    apart[nl] += aw;
#pragma unroll
                    for (int ct = 0; ct < 2; ++ct) {
                        float v = acc[rt][ct][r] + bqv[ct];
                        v = (v >= 0.f) ? v : NEG_SLOPE * v;
                        part[nl][ct] += aw * v;
                    }
                }
            }
#pragma unroll
            for (int nl = 0; nl < 2; ++nl) {
                apart[nl] += __shfl_xor(apart[nl], 16);
                apart[nl] += __shfl_xor(apart[nl], 32);
#pragma unroll
                for (int ct = 0; ct < 2; ++ct) {
                    part[nl][ct] += __shfl_xor(part[nl][ct], 16);
                    part[nl][ct] += __shfl_xor(part[nl][ct], 32);
                }
            }
            if (kg < 2) {  // lanes 0..31 -> the W(2) queue slot
                int nl = kg;
                long node = t * 4 + wr * 2 + nl;
                float den = apart[nl];
                if (den == 0.f) den = 1.f;
#pragma unroll
                for (int ct = 0; ct < 2; ++ct) {
                    int col = wc * 32 + ct * 16 + r16;
                    hagg[node * DHID + col] = part[nl][ct] / den;
                }
            }
        }
        __builtin_amdgcn_sched_barrier(0);
        // ---- prefetch alpha for tn (the A(4) queue slot)
#pragma unroll
        for (int rt = 0; rt < 4; ++rt)
            av4[rt] = *(const f32x4*)(alpha + Rn + wr * 64 + rt * 16 + kg * 4);
        __builtin_amdgcn_sched_barrier(0);

        if (last) break;
        t  = tn;
        R0 = Rn;
    }

#undef STAGE
#undef COMPUTE
}

// ---------------------------------------------------------------- kernel 2
// GEMM2: out = normalize(leaky(concat(h_node, hagg) @ Ww^T + bw))
// Tile: 128 nodes x 128 out, K=256 in 8 chunks of 32. hagg lives in `out`.
__global__ __launch_bounds__(256, 2) void gemm2_norm(
    const float* __restrict__ hnode,  // [NNODES][128]
    const float* __restrict__ bw,     // [128]
    const _Float16* __restrict__ ws,
    float* __restrict__ out)          // [NNODES][128], holds hagg on entry
{
    __shared__ _Float16 Ahi[8 * 520];
    __shared__ _Float16 Alo[8 * 520];
    __shared__ _Float16 Bhi[8 * 512];
    __shared__ _Float16 Blo[8 * 512];
    __shared__ float bw_s[128];
    __shared__ float nbuf[2][128];

    const int tid = threadIdx.x;
    const int l   = tid & 63;
    const int wid = tid >> 6;
    const int wr  = wid >> 1, wc = wid & 1;
    const long NB = (long)blockIdx.x * 128;

    if (tid < 128) bw_s[tid] = bw[tid];

    f32x4 acc[4][4];
#pragma unroll
    for (int i = 0; i < 4; ++i)
#pragma unroll
        for (int j = 0; j < 4; ++j) acc[i][j] = (f32x4){0.f, 0.f, 0.f, 0.f};

    const _Float16* wwh = ws + WS_WW_HI;
    const _Float16* wwl = ws + WS_WW_LO;

    for (int c = 0; c < 8; ++c) {
        __syncthreads();
        // ---- stage A: 128 nodes x 32 k of concat(h_node, hagg)
#pragma unroll
        for (int p = 0; p < 4; ++p) {
            int rl = p * 32 + (tid >> 3);
            long n = NB + rl;
            if (n > NNODES - 1) n = NNODES - 1;  // tail clamp (stores guarded)
            int kw = (tid & 7) * 4;       // within-chunk k
            int kgl = c * 32 + kw;        // global k in 0..255
            const float* g = (kgl < 128) ? (hnode + n * DIN + kgl)
                                         : (out + n * DHID + (kgl - 128));
            f32x4 v = *(const f32x4*)g;
            _Float16 h0 = (_Float16)v[0], h1 = (_Float16)v[1];
            _Float16 h2 = (_Float16)v[2], h3 = (_Float16)v[3];
            f16x4 vh = {h0, h1, h2, h3};
            f16x4 vl = {(_Float16)(v[0] - (float)h0), (_Float16)(v[1] - (float)h1),
                        (_Float16)(v[2] - (float)h2), (_Float16)(v[3] - (float)h3)};
            int lw  = (rl & 15) | (((kw >> 3) & 3) << 4);
            int s   = rl >> 4;
            int off = s * 520 + lw * 8 + (kw & 7);
            *(f16x4*)(Ahi + off) = vh;
            *(f16x4*)(Alo + off) = vl;
        }
        // ---- stage B slabs (g = c)
#pragma unroll
        for (int i = 0; i < 4; ++i) {
            int id = i * 256 + tid;
            int sb = id >> 6;
            int ls = id & 63;
            if (sb < 8) {
                *(f16x8*)(Bhi + sb * 512 + ls * 8) =
                    *(const f16x8*)(wwh + ((sb * 8 + c) * 64 + ls) * 8);
            } else {
                int ct = sb - 8;
                *(f16x8*)(Blo + ct * 512 + ls * 8) =
                    *(const f16x8*)(wwl + ((ct * 8 + c) * 64 + ls) * 8);
            }
        }
        __syncthreads();
        // ---- compute
        f16x8 ah[4], al[4], bh[4], bl[4];
#pragma unroll
        for (int rt = 0; rt < 4; ++rt) {
            int s = wr * 4 + rt;
            ah[rt] = *(const f16x8*)(Ahi + s * 520 + l * 8);
            al[rt] = *(const f16x8*)(Alo + s * 520 + l * 8);
        }
#pragma unroll
        for (int ct = 0; ct < 4; ++ct) {
            int s = wc * 4 + ct;
            bh[ct] = *(const f16x8*)(Bhi + s * 512 + l * 8);
            bl[ct] = *(const f16x8*)(Blo + s * 512 + l * 8);
        }
#pragma unroll
        for (int rt = 0; rt < 4; ++rt)
#pragma unroll
            for (int ct = 0; ct < 4; ++ct) {
                acc[rt][ct] = __builtin_amdgcn_mfma_f32_16x16x32_f16(ah[rt], bh[ct], acc[rt][ct], 0, 0, 0);
                acc[rt][ct] = __builtin_amdgcn_mfma_f32_16x16x32_f16(ah[rt], bl[ct], acc[rt][ct], 0, 0, 0);
                acc[rt][ct] = __builtin_amdgcn_mfma_f32_16x16x32_f16(al[rt], bh[ct], acc[rt][ct], 0, 0, 0);
            }
    }

    // ---- epilogue: +bw, leaky, row L2-norm (128 cols), safediv, store
    const int grp = l >> 4;
#pragma unroll
    for (int rt = 0; rt < 4; ++rt)
#pragma unroll
        for (int ct = 0; ct < 4; ++ct)
#pragma unroll
            for (int r = 0; r < 4; ++r) {
                int col = wc * 64 + ct * 16 + (l & 15);
                float v = acc[rt][ct][r] + bw_s[col];
                acc[rt][ct][r] = (v >= 0.f) ? v : NEG_SLOPE * v;
            }
    float ssq[4][4];
#pragma unroll
    for (int rt = 0; rt < 4; ++rt)
#pragma unroll
        for (int r = 0; r < 4; ++r) {
            float s = 0.f;
#pragma unroll
            for (int ct = 0; ct < 4; ++ct) s += acc[rt][ct][r] * acc[rt][ct][r];
            s += __shfl_xor(s, 1);
            s += __shfl_xor(s, 2);
            s += __shfl_xor(s, 4);
            s += __shfl_xor(s, 8);
            ssq[rt][r] = s;  // sum over this wave's 64 cols
        }
    if ((l & 15) == 0) {
#pragma unroll
        for (int rt = 0; rt < 4; ++rt)
#pragma unroll
            for (int r = 0; r < 4; ++r)
                nbuf[wc][wr * 64 + rt * 16 + grp * 4 + r] = ssq[rt][r];
    }
    __syncthreads();
#pragma unroll
    for (int rt = 0; rt < 4; ++rt)
#pragma unroll
        for (int r = 0; r < 4; ++r) {
            int rowl = wr * 64 + rt * 16 + grp * 4 + r;
            long n = NB + rowl;
            if (n < NNODES) {
                float nrm = sqrtf(nbuf[0][rowl] + nbuf[1][rowl]);
                if (nrm == 0.f) nrm = 1.f;
#pragma unroll
                for (int ct = 0; ct < 4; ++ct) {
                    int col = wc * 64 + ct * 16 + (l & 15);
                    out[n * DOUT + col] = acc[rt][ct][r] / nrm;
                }
            }
        }
}

// ---------------------------------------------------------------- launcher
extern "C" void kernel_launch(void* const* d_in, const int* in_sizes, int n_in,
                              void* d_out, int out_size, void* d_ws, size_t ws_size,
                              hipStream_t stream) {
    const float* h_node  = (const float*)d_in[0];
    const float* h_ngbrs = (const float*)d_in[1];
    const float* alpha   = (const float*)d_in[2];
    const float* Wq      = (const float*)d_in[3];
    const float* bq      = (const float*)d_in[4];
    const float* Ww      = (const float*)d_in[5];
    const float* bw      = (const float*)d_in[6];
    float* out   = (float*)d_out;
    _Float16* ws = (_Float16*)d_ws;

    convert_weights<<<24, 256, 0, stream>>>(Wq, Ww, ws);
    gemm1_agg<<<GG, 512, 0, stream>>>(h_ngbrs, alpha, bq, ws, out);
    // ceil(50000/128) = 391 node tiles
    gemm2_norm<<<391, 256, 0, stream>>>(h_node, bw, ws, out);
}

// Round 9
// 228.623 us; speedup vs baseline: 1.3066x; 1.3066x over previous
//
#include <hip/hip_runtime.h>

#define NNODES 50000
#define DIN 128
#define DHID 128
#define DOUT 128
#define NEG_SLOPE 0.01f
#define NT 12500   // 1,600,000 rows / 128
#define GG 256     // persistent grid: 1 block per CU

typedef _Float16 f16x8 __attribute__((ext_vector_type(8)));
typedef _Float16 f16x4 __attribute__((ext_vector_type(4)));
typedef _Float16 f16x2 __attribute__((ext_vector_type(2)));
typedef float f32x4 __attribute__((ext_vector_type(4)));

__device__ __forceinline__ f16x2 pkrtz(float a, float b) {
    // __builtin_amdgcn_cvt_pkrtz returns __fp16x2; bit-identical to f16x2
    return __builtin_bit_cast(f16x2, __builtin_amdgcn_cvt_pkrtz(a, b));
}

// d_ws layout (halves):
//  WqB hi: [ct(8)][g(4)][l(64)][8]   = 16384 halves
//  WqB lo: 16384
//  WwB hi: [ct(8)][g(8)][l(64)][8]   = 32768 halves
//  WwB lo: 32768
#define WS_WQ_HI 0
#define WS_WQ_LO 16384
#define WS_WW_HI 32768
#define WS_WW_LO 65536

__device__ __forceinline__ void gload_lds16(const float* g, float* lds) {
    __builtin_amdgcn_global_load_lds(
        (const __attribute__((address_space(1))) void*)g,
        (__attribute__((address_space(3))) void*)lds, 16, 0, 0);
}

// ---------------------------------------------------------------- kernel 0
// Convert weights to fp16 hi/lo fragment slabs.
// Fragment convention (mfma_f32_16x16x32_f16):
//   A: row = l&15, k = (l>>4)*8 + j
//   B: col = l&15, k = (l>>4)*8 + j
//   D: col = l&15, row = (l>>4)*4 + r
__global__ void convert_weights(const float* __restrict__ Wq,
                                const float* __restrict__ Ww,
                                _Float16* __restrict__ ws) {
    int id = blockIdx.x * 256 + threadIdx.x;
    if (id < 2048) {  // Wq slots: B[k][col] = Wq[col][k]
        int s  = id;
        int l  = s & 63;
        int g  = (s >> 6) & 3;
        int ct = s >> 8;
        int col = ct * 16 + (l & 15);
        int k0  = g * 32 + (l >> 4) * 8;
        const float* src = Wq + col * DIN + k0;
        f16x8 vh, vl;
#pragma unroll
        for (int j = 0; j < 8; ++j) {
            float v = src[j];
            _Float16 h = (_Float16)v;
            vh[j] = h;
            vl[j] = (_Float16)(v - (float)h);
        }
        *(f16x8*)(ws + WS_WQ_HI + s * 8) = vh;
        *(f16x8*)(ws + WS_WQ_LO + s * 8) = vl;
    } else if (id < 2048 + 4096) {  // Ww slots: B2[k][o] = Ww[o][k]
        int s  = id - 2048;
        int l  = s & 63;
        int g  = (s >> 6) & 7;
        int ct = s >> 9;
        int col = ct * 16 + (l & 15);
        int k0  = g * 32 + (l >> 4) * 8;
        const float* src = Ww + col * (DIN + DHID) + k0;
        f16x8 vh, vl;
#pragma unroll
        for (int j = 0; j < 8; ++j) {
            float v = src[j];
            _Float16 h = (_Float16)v;
            vh[j] = h;
            vl[j] = (_Float16)(v - (float)h);
        }
        *(f16x8*)(ws + WS_WW_HI + s * 8) = vh;
        *(f16x8*)(ws + WS_WW_LO + s * 8) = vl;
    }
}

// ---------------------------------------------------------------- kernel 1
// GEMM1 + leaky + alpha-weighted mean -> hagg (= d_out).
// Persistent ring pipeline (R7 structure, proven): 8 waves (2x4), wave
// tile 64x32, 4 x 16KB LDS slab ring, counted vmcnt(10,10,10,4), full
// prologue drain. A converted to SINGLE f16 via v_cvt_pkrtz (4 instrs
// per fragment vs ~32 for hi/lo split); B stays f16 hi+lo (pre-converted,
// free). MFMA terms 3 -> 2. Error budget: A-RTZ rel 2^-10 -> end-to-end
// absmax ~3-6e-3 < 1.11e-2 threshold.
__global__ __launch_bounds__(512, 2) void gemm1_agg(
    const float* __restrict__ hng,    // [NNODES*32][128]
    const float* __restrict__ alpha,  // [NNODES*32]
    const float* __restrict__ bq,     // [128]
    const _Float16* __restrict__ ws,
    float* __restrict__ hagg)         // [NNODES][128]
{
    __shared__ float As[4][4096];  // 4-slab ring, 64KB

    const int tid = threadIdx.x;
    const int l   = tid & 63;
    const int wid = tid >> 6;          // 0..7
    const int wr  = wid >> 2;          // 0..1  (row group: 64 rows)
    const int wc  = wid & 3;           // 0..3  (col group: 32 cols)
    const int r16 = l & 15;
    const int kg  = l >> 4;
    const int srow = l >> 3;                 // 0..7 within stage instr
    const int scol = ((l & 7) ^ srow) * 4;   // pre-swizzled src float offset

    const _Float16* wqh = ws + WS_WQ_HI;
    const _Float16* wql = ws + WS_WQ_LO;

    // ---- permanent B fragments: 4 chunks x 2 col-tiles, hi+lo (64 VGPR)
    f16x8 bh[4][2], bl[4][2];
#pragma unroll
    for (int c = 0; c < 4; ++c)
#pragma unroll
        for (int ct = 0; ct < 2; ++ct) {
            int off = (((wc * 2 + ct) * 4 + c) * 64 + l) * 8;
            bh[c][ct] = *(const f16x8*)(wqh + off);
            bl[c][ct] = *(const f16x8*)(wql + off);
        }

    // per-lane global base for staging; per use add (Rb + {0,64})*DIN and
    // the chunk column offset c*32
    const float* hb = hng + (wid * 8 + srow) * DIN + scol;

#define STAGE(Rb, c)                                                          \
    do {                                                                      \
        gload_lds16(hb + (Rb)*DIN + (c) * 32, &As[c][(wid * 8) * 32]);        \
        gload_lds16(hb + ((Rb) + 64) * DIN + (c) * 32,                        \
                    &As[c][(64 + wid * 8) * 32]);                             \
    } while (0)

#define COMPUTE(c)                                                            \
    do {                                                                      \
        _Pragma("unroll")                                                     \
        for (int rt_ = 0; rt_ < 4; ++rt_) {                                   \
            int row_ = wr * 64 + rt_ * 16 + r16;                              \
            int sw_  = (r16 & 7) << 4;                                        \
            const char* rb_ = (const char*)&As[c][row_ * 32];                 \
            f32x4 v0_ = *(const f32x4*)(rb_ + ((kg * 32 + 0) ^ sw_));         \
            f32x4 v1_ = *(const f32x4*)(rb_ + ((kg * 32 + 16) ^ sw_));        \
            f16x2 p0_ = pkrtz(v0_[0], v0_[1]);                                \
            f16x2 p1_ = pkrtz(v0_[2], v0_[3]);                                \
            f16x2 p2_ = pkrtz(v1_[0], v1_[1]);                                \
            f16x2 p3_ = pkrtz(v1_[2], v1_[3]);                                \
            f16x8 ah_;                                                        \
            ah_[0] = p0_[0]; ah_[1] = p0_[1];                                 \
            ah_[2] = p1_[0]; ah_[3] = p1_[1];                                 \
            ah_[4] = p2_[0]; ah_[5] = p2_[1];                                 \
            ah_[6] = p3_[0]; ah_[7] = p3_[1];                                 \
            _Pragma("unroll")                                                 \
            for (int ct_ = 0; ct_ < 2; ++ct_) {                               \
                acc[rt_][ct_] = __builtin_amdgcn_mfma_f32_16x16x32_f16(       \
                    ah_, bh[c][ct_], acc[rt_][ct_], 0, 0, 0);                 \
                acc[rt_][ct_] = __builtin_amdgcn_mfma_f32_16x16x32_f16(       \
                    ah_, bl[c][ct_], acc[rt_][ct_], 0, 0, 0);                 \
            }                                                                 \
        }                                                                     \
    } while (0)

    long t  = blockIdx.x;
    long R0 = t * 128;

    // ---- prologue (issue order irrelevant — fully drained below)
    STAGE(R0, 0);
    STAGE(R0, 1);
    STAGE(R0, 2);
    float bqv[2];
#pragma unroll
    for (int ct = 0; ct < 2; ++ct)
        bqv[ct] = bq[wc * 32 + ct * 16 + r16];
    f32x4 av4[4];
#pragma unroll
    for (int rt = 0; rt < 4; ++rt)
        av4[rt] = *(const f32x4*)(alpha + R0 + wr * 64 + rt * 16 + kg * 4);
    // full drain: iter-0 wait ladder is order-robust
    asm volatile("s_waitcnt vmcnt(0)" ::: "memory");
    __builtin_amdgcn_s_barrier();
    __builtin_amdgcn_sched_barrier(0);

    for (;;) {
        const bool last = (t + GG >= NT);
        const long tn   = last ? t : t + GG;   // clamped prefetch target
        const long Rn   = tn * 128;

        f32x4 acc[4][2];
#pragma unroll
        for (int i = 0; i < 4; ++i)
#pragma unroll
            for (int j = 0; j < 2; ++j) acc[i][j] = (f32x4){0.f, 0.f, 0.f, 0.f};

        // ---- c0: need S(t,0); steady outstanding = S0,S1,S2,W,A = 12
        asm volatile("s_waitcnt vmcnt(10)" ::: "memory");
        __builtin_amdgcn_s_barrier();
        __builtin_amdgcn_sched_barrier(0);
        STAGE(R0, 3);
        __builtin_amdgcn_sched_barrier(0);
        COMPUTE(0);
        // ---- c1: need S(t,1); outstanding = S1,S2,W,A,S3 = 12
        asm volatile("s_waitcnt vmcnt(10)" ::: "memory");
        __builtin_amdgcn_s_barrier();
        __builtin_amdgcn_sched_barrier(0);
        STAGE(Rn, 0);
        __builtin_amdgcn_sched_barrier(0);
        COMPUTE(1);
        // ---- c2: need S(t,2); outstanding = S2,W,A,S3,Sn0 = 12
        asm volatile("s_waitcnt vmcnt(10)" ::: "memory");
        __builtin_amdgcn_s_barrier();
        __builtin_amdgcn_sched_barrier(0);
        STAGE(Rn, 1);
        __builtin_amdgcn_sched_barrier(0);
        COMPUTE(2);
        // ---- c3: need S(t,3) (also retires W,A); leaves Sn0,Sn1 = 4
        asm volatile("s_waitcnt vmcnt(4)" ::: "memory");
        __builtin_amdgcn_s_barrier();
        __builtin_amdgcn_sched_barrier(0);
        STAGE(Rn, 2);
        __builtin_amdgcn_sched_barrier(0);
        COMPUTE(3);
        __builtin_amdgcn_sched_barrier(0);

        // ---- epilogue tile t: +bq, leaky, *alpha, reduce 32 rows/node
        {
            float part[2][2] = {{0.f, 0.f}, {0.f, 0.f}};
            float apart[2] = {0.f, 0.f};
#pragma unroll
            for (int rt = 0; rt < 4; ++rt) {
                const int nl = rt >> 1;
#pragma unroll
                for (int r = 0; r < 4; ++r) {
                    float aw = av4[rt][r];
                    apart[nl] += aw;
#pragma unroll
                    for (int ct = 0; ct < 2; ++ct) {
                        float v = acc[rt][ct][r] + bqv[ct];
                        v = (v >= 0.f) ? v : NEG_SLOPE * v;
                        part[nl][ct] += aw * v;
                    }
                }
            }
#pragma unroll
            for (int nl = 0; nl < 2; ++nl) {
                apart[nl] += __shfl_xor(apart[nl], 16);
                apart[nl] += __shfl_xor(apart[nl], 32);
#pragma unroll
                for (int ct = 0; ct < 2; ++ct) {
                    part[nl][ct] += __shfl_xor(part[nl][ct], 16);
                    part[nl][ct] += __shfl_xor(part[nl][ct], 32);
                }
            }
            if (kg < 2) {  // lanes 0..31 -> the W(2) queue slot
                int nl = kg;
                long node = t * 4 + wr * 2 + nl;
                float den = apart[nl];
                if (den == 0.f) den = 1.f;
#pragma unroll
                for (int ct = 0; ct < 2; ++ct) {
                    int col = wc * 32 + ct * 16 + r16;
                    hagg[node * DHID + col] = part[nl][ct] / den;
                }
            }
        }
        __builtin_amdgcn_sched_barrier(0);
        // ---- prefetch alpha for tn (the A(4) queue slot)
#pragma unroll
        for (int rt = 0; rt < 4; ++rt)
            av4[rt] = *(const f32x4*)(alpha + Rn + wr * 64 + rt * 16 + kg * 4);
        __builtin_amdgcn_sched_barrier(0);

        if (last) break;
        t  = tn;
        R0 = Rn;
    }

#undef STAGE
#undef COMPUTE
}

// ---------------------------------------------------------------- kernel 2
// GEMM2: out = normalize(leaky(concat(h_node, hagg) @ Ww^T + bw))
// Tile: 128 nodes x 128 out, K=256 in 8 chunks of 32. hagg lives in `out`.
// A single-f16 via pkrtz (Alo buffer dropped); B hi+lo; 2 MFMA terms.
__global__ __launch_bounds__(256, 2) void gemm2_norm(
    const float* __restrict__ hnode,  // [NNODES][128]
    const float* __restrict__ bw,     // [128]
    const _Float16* __restrict__ ws,
    float* __restrict__ out)          // [NNODES][128], holds hagg on entry
{
    __shared__ _Float16 Ahi[8 * 520];
    __shared__ _Float16 Bhi[8 * 512];
    __shared__ _Float16 Blo[8 * 512];
    __shared__ float bw_s[128];
    __shared__ float nbuf[2][128];

    const int tid = threadIdx.x;
    const int l   = tid & 63;
    const int wid = tid >> 6;
    const int wr  = wid >> 1, wc = wid & 1;
    const long NB = (long)blockIdx.x * 128;

    if (tid < 128) bw_s[tid] = bw[tid];

    f32x4 acc[4][4];
#pragma unroll
    for (int i = 0; i < 4; ++i)
#pragma unroll
        for (int j = 0; j < 4; ++j) acc[i][j] = (f32x4){0.f, 0.f, 0.f, 0.f};

    const _Float16* wwh = ws + WS_WW_HI;
    const _Float16* wwl = ws + WS_WW_LO;

    for (int c = 0; c < 8; ++c) {
        __syncthreads();
        // ---- stage A: 128 nodes x 32 k of concat(h_node, hagg), f16 single
#pragma unroll
        for (int p = 0; p < 4; ++p) {
            int rl = p * 32 + (tid >> 3);
            long n = NB + rl;
            if (n > NNODES - 1) n = NNODES - 1;  // tail clamp (stores guarded)
            int kw = (tid & 7) * 4;       // within-chunk k
            int kgl = c * 32 + kw;        // global k in 0..255
            const float* g = (kgl < 128) ? (hnode + n * DIN + kgl)
                                         : (out + n * DHID + (kgl - 128));
            f32x4 v = *(const f32x4*)g;
            f16x2 p0 = pkrtz(v[0], v[1]);
            f16x2 p1 = pkrtz(v[2], v[3]);
            f16x4 vh;
            vh[0] = p0[0]; vh[1] = p0[1]; vh[2] = p1[0]; vh[3] = p1[1];
            int lw  = (rl & 15) | (((kw >> 3) & 3) << 4);
            int s   = rl >> 4;
            int off = s * 520 + lw * 8 + (kw & 7);
            *(f16x4*)(Ahi + off) = vh;
        }
        // ---- stage B slabs (g = c)
#pragma unroll
        for (int i = 0; i < 4; ++i) {
            int id = i * 256 + tid;
            int sb = id >> 6;
            int ls = id & 63;
            if (sb < 8) {
                *(f16x8*)(Bhi + sb * 512 + ls * 8) =
                    *(const f16x8*)(wwh + ((sb * 8 + c) * 64 + ls) * 8);
            } else {
                int ct = sb - 8;
                *(f16x8*)(Blo + ct * 512 + ls * 8) =
                    *(const f16x8*)(wwl + ((ct * 8 + c) * 64 + ls) * 8);
            }
        }
        __syncthreads();
        // ---- compute
        f16x8 ah[4], bh[4], bl[4];
#pragma unroll
        for (int rt = 0; rt < 4; ++rt) {
            int s = wr * 4 + rt;
            ah[rt] = *(const f16x8*)(Ahi + s * 520 + l * 8);
        }
#pragma unroll
        for (int ct = 0; ct < 4; ++ct) {
            int s = wc * 4 + ct;
            bh[ct] = *(const f16x8*)(Bhi + s * 512 + l * 8);
            bl[ct] = *(const f16x8*)(Blo + s * 512 + l * 8);
        }
#pragma unroll
        for (int rt = 0; rt < 4; ++rt)
#pragma unroll
            for (int ct = 0; ct < 4; ++ct) {
                acc[rt][ct] = __builtin_amdgcn_mfma_f32_16x16x32_f16(ah[rt], bh[ct], acc[rt][ct], 0, 0, 0);
                acc[rt][ct] = __builtin_amdgcn_mfma_f32_16x16x32_f16(ah[rt], bl[ct], acc[rt][ct], 0, 0, 0);
            }
    }

    // ---- epilogue: +bw, leaky, row L2-norm (128 cols), safediv, store
    const int grp = l >> 4;
#pragma unroll
    for (int rt = 0; rt < 4; ++rt)
#pragma unroll
        for (int ct = 0; ct < 4; ++ct)
#pragma unroll
            for (int r = 0; r < 4; ++r) {
                int col = wc * 64 + ct * 16 + (l & 15);
                float v = acc[rt][ct][r] + bw_s[col];
                acc[rt][ct][r] = (v >= 0.f) ? v : NEG_SLOPE * v;
            }
    float ssq[4][4];
#pragma unroll
    for (int rt = 0; rt < 4; ++rt)
#pragma unroll
        for (int r = 0; r < 4; ++r) {
            float s = 0.f;
#pragma unroll
            for (int ct = 0; ct < 4; ++ct) s += acc[rt][ct][r] * acc[rt][ct][r];
            s += __shfl_xor(s, 1);
            s += __shfl_xor(s, 2);
            s += __shfl_xor(s, 4);
            s += __shfl_xor(s, 8);
            ssq[rt][r] = s;  // sum over this wave's 64 cols
        }
    if ((l & 15) == 0) {
#pragma unroll
        for (int rt = 0; rt < 4; ++rt)
#pragma unroll
            for (int r = 0; r < 4; ++r)
                nbuf[wc][wr * 64 + rt * 16 + grp * 4 + r] = ssq[rt][r];
    }
    __syncthreads();
#pragma unroll
    for (int rt = 0; rt < 4; ++rt)
#pragma unroll
        for (int r = 0; r < 4; ++r) {
            int rowl = wr * 64 + rt * 16 + grp * 4 + r;
            long n = NB + rowl;
            if (n < NNODES) {
                float nrm = sqrtf(nbuf[0][rowl] + nbuf[1][rowl]);
                if (nrm == 0.f) nrm = 1.f;
#pragma unroll
                for (int ct = 0; ct < 4; ++ct) {
                    int col = wc * 64 + ct * 16 + (l & 15);
                    out[n * DOUT + col] = acc[rt][ct][r] / nrm;
                }
            }
        }
}

// ---------------------------------------------------------------- launcher
extern "C" void kernel_launch(void* const* d_in, const int* in_sizes, int n_in,
                              void* d_out, int out_size, void* d_ws, size_t ws_size,
                              hipStream_t stream) {
    const float* h_node  = (const float*)d_in[0];
    const float* h_ngbrs = (const float*)d_in[1];
    const float* alpha   = (const float*)d_in[2];
    const float* Wq      = (const float*)d_in[3];
    const float* bq      = (const float*)d_in[4];
    const float* Ww      = (const float*)d_in[5];
    const float* bw      = (const float*)d_in[6];
    float* out   = (float*)d_out;
    _Float16* ws = (_Float16*)d_ws;

    convert_weights<<<24, 256, 0, stream>>>(Wq, Ww, ws);
    gemm1_agg<<<GG, 512, 0, stream>>>(h_ngbrs, alpha, bq, ws, out);
    // ceil(50000/128) = 391 node tiles
    gemm2_norm<<<391, 256, 0, stream>>>(h_node, bw, ws, out);
}